// Round 8
// baseline (66.238 us; speedup 1.0000x reference)
//
#include <hip/hip_runtime.h>

// CostVolume2D: B=8, H=256, W=512, C=32, n_disp=12, stride=1.
// cost[b,h,w,d] = sum_c |feat_l[b,h,w,c] - feat_r[b,h,w-d,c]|, feat_r zero-padded left.
//
// Block = 256 threads = half a row, 1 pixel/thread, TWO channel passes (16 ch each).
// Per pass, feat_r tile (267 cols x 4 float4-planes) staged DIRECTLY into
// plane-major LDS by global_load_lds (no reg staging -> no spill; verified r7):
//   lds4[ql][colr], ql = local plane 0..3, colr in [0,266], NCOL=272.
//   wave w stages plane w: dest = lane-consecutive chunks (legal linear glld),
//   source = col*128B + quarter*16B scatter (L2 merges sectors; FETCH stayed
//   compulsory in r7 with the same pattern).
// Reads: fixed (ql,d) -> lane-consecutive chunks, one base + 12 imm offsets
//   (measured 0 bank conflicts in r4/r5/r7).
// Why split: r7 had all pipes <30% busy, occupancy 27% (4 blocks/CU @ 34.8KB).
//   17.4KB/block -> 8 blocks/CU resident: phase overlap across blocks.

constexpr int Wd   = 512;
constexpr int ND   = 12;
constexpr int NCOL = 272;             // per-plane chunk capacity (267 used)

typedef float vfloat4 __attribute__((ext_vector_type(4)));

__device__ __forceinline__ float l1_4(float4 a, float4 b) {
    return fabsf(a.x - b.x) + fabsf(a.y - b.y) + fabsf(a.z - b.z) + fabsf(a.w - b.w);
}

__global__ __launch_bounds__(256) void cost_volume_kernel(
    const float* __restrict__ fl,
    const float* __restrict__ fr,
    float* __restrict__ out)
{
    __shared__ float4 lds4[4 * NCOL];          // 17408 B

    const int t    = threadIdx.x;
    const int wave = t >> 6;
    const int lane = t & 63;
    const int wstart = (blockIdx.x & 1) * 256;
    const int bh     = blockIdx.x >> 1;        // b*H + h
    const float* fr_row = fr + (size_t)bh * Wd * 32;

    const int w = wstart + t;
    const size_t pix = (size_t)bh * Wd + w;
    const float4* lp = reinterpret_cast<const float4*>(fl) + pix * 8;

    float res[ND];
    #pragma unroll
    for (int d = 0; d < ND; ++d) res[d] = 0.f;
    float lsum = 0.f;

    #pragma unroll
    for (int h = 0; h < 2; ++h) {
        if (h == 1) __syncthreads();           // pass-0 LDS reads complete first

        // ---- stage feat_r channel-half h: wave w stages plane w (global quarter h*4+w)
        #pragma unroll
        for (int run = 0; run < 5; ++run) {
            const int colr = run * 64 + lane;
            int col = wstart - 11 + colr;
            col = max(col, 0);                 // guard cols: clamped, never used
            if (run < 4 || lane < 267 - 256) {
                __builtin_amdgcn_global_load_lds(
                    (const __attribute__((address_space(1))) void*)(fr_row + (size_t)col * 32 + (h * 4 + wave) * 4),
                    (__attribute__((address_space(3))) void*)(lds4 + wave * NCOL + colr),
                    16, 0, 0);
            }
        }

        // ---- feat_l channel-half h into registers (overlaps glld latency)
        float4 L[4];
        #pragma unroll
        for (int ql = 0; ql < 4; ++ql) {
            L[ql] = lp[h * 4 + ql];
            lsum += fabsf(L[ql].x) + fabsf(L[ql].y) + fabsf(L[ql].z) + fabsf(L[ql].w);
        }

        __syncthreads();                       // drains glld (vmcnt) + visibility

        // ---- 12 disparities from this half: per plane one base + 12 imm offsets
        #pragma unroll
        for (int ql = 0; ql < 4; ++ql) {
            const float4 Lq = L[ql];
            const float4* base = &lds4[ql * NCOL + t];   // colr = t + (11-d)
            #pragma unroll
            for (int d = 0; d < ND; ++d) {
                res[d] += l1_4(Lq, base[11 - d]);
            }
        }
    }

    // ---- left edge: w < d -> feat_r fully shifted out (zeros) -> sum|feat_l|
    #pragma unroll
    for (int d = 0; d < ND; ++d)
        if (w < d) res[d] = lsum;

    // ---- nontemporal output stores (don't evict inputs from L3)
    vfloat4* op = reinterpret_cast<vfloat4*>(out + pix * ND);
    vfloat4 o0 = {res[0], res[1], res[2],  res[3]};
    vfloat4 o1 = {res[4], res[5], res[6],  res[7]};
    vfloat4 o2 = {res[8], res[9], res[10], res[11]};
    __builtin_nontemporal_store(o0, op + 0);
    __builtin_nontemporal_store(o1, op + 1);
    __builtin_nontemporal_store(o2, op + 2);
}

extern "C" void kernel_launch(void* const* d_in, const int* in_sizes, int n_in,
                              void* d_out, int out_size, void* d_ws, size_t ws_size,
                              hipStream_t stream)
{
    const float* fl = (const float*)d_in[0];
    const float* fr = (const float*)d_in[1];
    float* out = (float*)d_out;

    const int grid = 8 * 256 * 2;              // (b,h) x 2 half-rows
    cost_volume_kernel<<<grid, 256, 0, stream>>>(fl, fr, out);
}